// Round 1
// baseline (144.021 us; speedup 1.0000x reference)
//
#include <hip/hip_runtime.h>
#include <hip/hip_bf16.h>

// Problem constants
constexpr int cB = 4;
constexpr int cN = 4096;
constexpr int cD = 512;
constexpr int cK = 64;
constexpr int cNB = cB * cN;       // 16384 rows
constexpr int cNP = cN + 1;        // 4097 prefix rows
constexpr int cCS = 16;            // chunk size for scans
constexpr int cNC = cN / cCS;      // 256 chunks per batch
constexpr int cNC1 = cNC + 1;      // 257

typedef unsigned short u16;
typedef unsigned int u32;
typedef unsigned long long u64;
typedef __bf16 bf16x8 __attribute__((ext_vector_type(8)));
typedef float f32x4 __attribute__((ext_vector_type(4)));

// ---- workspace layout (in floats) ----
constexpr size_t OFF_H    = 0;                                  // cNB*cK
constexpr size_t OFF_T1   = OFF_H    + (size_t)cNB * cK;        // cNB
constexpr size_t OFF_T2   = OFF_T1   + cNB;                     // cNB
constexpr size_t OFF_T2S  = OFF_T2   + cNB;                     // cNB (sorted)
constexpr size_t OFF_IDX  = OFF_T2S  + cNB;                     // cNB (int)
constexpr size_t OFF_P    = OFF_IDX  + cNB;                     // cNB (int) split point per row
constexpr size_t OFF_EPL  = OFF_P    + cNB;                     // cB*cNP*cK
constexpr size_t OFF_GNL  = OFF_EPL  + (size_t)cB * cNP * cK;   // cB*cNP*cK
constexpr size_t OFF_EPS  = OFF_GNL  + (size_t)cB * cNP * cK;   // cB*cNP
constexpr size_t OFF_GNS  = OFF_EPS  + (size_t)cB * cNP;        // cB*cNP
constexpr size_t OFF_CHE  = OFF_GNS  + (size_t)cB * cNP;        // cB*cNC*cK
constexpr size_t OFF_CHG  = OFF_CHE  + (size_t)cB * cNC * cK;
constexpr size_t OFF_CHES = OFF_CHG  + (size_t)cB * cNC * cK;   // cB*cNC
constexpr size_t OFF_CHGS = OFF_CHES + (size_t)cB * cNC;
constexpr size_t OFF_OFE  = OFF_CHGS + (size_t)cB * cNC;        // cB*cNC1*cK
constexpr size_t OFF_OFG  = OFF_OFE  + (size_t)cB * cNC1 * cK;
constexpr size_t OFF_OFES = OFF_OFG  + (size_t)cB * cNC1 * cK;  // cB*cNC1
constexpr size_t OFF_OFGS = OFF_OFES + (size_t)cB * cNC1;
constexpr size_t OFF_XB16 = OFF_OFGS + (size_t)cB * cNC1;       // cNB*cD u16 = /2 floats
constexpr size_t OFF_WB16 = OFF_XB16 + (size_t)cNB * cD / 2;    // cK*cD u16

__device__ __forceinline__ u16 f2bf(float f) {
    unsigned u = __float_as_uint(f);
    u += 0x7fffu + ((u >> 16) & 1u);   // RNE
    return (u16)(u >> 16);
}
__device__ __forceinline__ u32 pk2(float a, float b) {
    return (u32)f2bf(a) | ((u32)f2bf(b) << 16);
}
// monotone float -> sortable uint (ascending)
__device__ __forceinline__ u32 f2sort(float f) {
    u32 b = __float_as_uint(f);
    u32 mask = (u32)((int)b >> 31);
    return b ^ (mask | 0x80000000u);
}

// ---------------------------------------------------------------------------
// k_prep (544 blocks): blocks <512: one pass over x -> xb16 (bf16) + exact
// f32 t1/t2 via in-block fold of Wa with Wb/Wc. Blocks >=512: Wa -> wab16.
// ---------------------------------------------------------------------------
__global__ __launch_bounds__(256) void k_prep(
    const float* __restrict__ x, const float* __restrict__ Wa,
    const float* __restrict__ Wb, const float* __restrict__ wbb,
    const float* __restrict__ Wc, const float* __restrict__ wcb,
    u16* __restrict__ xb16, u16* __restrict__ wab16,
    float* __restrict__ t1, float* __restrict__ t2)
{
    __shared__ float wabL[cD], wacL[cD];
    int t = threadIdx.x;
    if (blockIdx.x >= 512) {           // wprep slice: 32 blocks x 256 x 4 elems
        int i4 = (((int)blockIdx.x - 512) * 256 + t) * 4;
        float4 v = *(const float4*)(Wa + i4);
        uint2 p = {pk2(v.x, v.y), pk2(v.z, v.w)};
        *(uint2*)(wab16 + i4) = p;
        return;
    }
    float s1a = 0.f, s2a = 0.f, s1b = 0.f, s2b = 0.f;
#pragma unroll 8
    for (int k = 0; k < cK; ++k) {
        float wbk = Wb[k], wck = Wc[k];
        float wa1 = Wa[k * cD + t];
        float wa2 = Wa[k * cD + t + 256];
        s1a += wa1 * wbk; s2a += wa1 * wck;
        s1b += wa2 * wbk; s2b += wa2 * wck;
    }
    wabL[t] = s1a; wacL[t] = s2a; wabL[t + 256] = s1b; wacL[t + 256] = s2b;
    __syncthreads();

    int w = t >> 6, lane = t & 63;
    int d1 = lane * 4, d2 = 256 + lane * 4;
    float4 wbA = *(const float4*)&wabL[d1], wbB = *(const float4*)&wabL[d2];
    float4 wcA = *(const float4*)&wacL[d1], wcB = *(const float4*)&wacL[d2];
    float wbbv = wbb[0], wcbv = wcb[0];
#pragma unroll 2
    for (int rr = 0; rr < 8; ++rr) {
        int row = blockIdx.x * 32 + w * 8 + rr;
        const float* xp = x + (size_t)row * cD;
        float4 a  = *(const float4*)(xp + d1);
        float4 bq = *(const float4*)(xp + d2);
        uint2 pa = {pk2(a.x, a.y), pk2(a.z, a.w)};
        uint2 pb = {pk2(bq.x, bq.y), pk2(bq.z, bq.w)};
        *(uint2*)(xb16 + (size_t)row * cD + d1) = pa;
        *(uint2*)(xb16 + (size_t)row * cD + d2) = pb;
        float p1 = a.x*wbA.x + a.y*wbA.y + a.z*wbA.z + a.w*wbA.w
                 + bq.x*wbB.x + bq.y*wbB.y + bq.z*wbB.z + bq.w*wbB.w;
        float p2 = a.x*wcA.x + a.y*wcA.y + a.z*wcA.z + a.w*wcA.w
                 + bq.x*wcB.x + bq.y*wcB.y + bq.z*wcB.z + bq.w*wcB.w;
#pragma unroll
        for (int off = 32; off > 0; off >>= 1) {
            p1 += __shfl_down(p1, off, 64);
            p2 += __shfl_down(p2, off, 64);
        }
        if (lane == 0) { t1[row] = p1 + wbbv; t2[row] = p2 + wcbv; }
    }
}

// ---------------------------------------------------------------------------
// k_projrank (512 blocks): blocks <256 do the bf16-MFMA GEMM tile (64 rows);
// blocks >=256 do register-resident ballot rank: each wave holds 1024
// composite keys in VGPRs (16 u64/lane); per row, count = popc(ballot(key <
// thr)) summed on the SALU pipe -- zero LDS in the hot loop. The same pass
// also counts p_i = #{t2_j < -t1_i} (u32 compare on key hi-words), removing
// k_out's binary search. LDS now 8 KB/block (was 33.75 KB).
// ---------------------------------------------------------------------------
__global__ __launch_bounds__(256) void k_projrank(
    const u16* __restrict__ xb16, const u16* __restrict__ wab16,
    const float* __restrict__ t1, const float* __restrict__ t2,
    float* __restrict__ h, float* __restrict__ t2s, int* __restrict__ idxs,
    int* __restrict__ pidx)
{
    __shared__ __align__(16) u64 shbuf[1024];   // 8 KB: GEMM xs/was OR rank partials
    int t = threadIdx.x;
    if (blockIdx.x < 256) {
        u16* xs = (u16*)shbuf;
        u16* was = xs + 64 * 32;
        int rowbase = blockIdx.x * 64;
        int w = t >> 6, lane = t & 63, m = lane & 15, quad = lane >> 4;
        int grow = w * 16 + (lane >> 2);
        int gcol = (lane & 3) * 8;
        const u16* xg = xb16 + (size_t)(rowbase + grow) * cD + gcol;
        const u16* wg = wab16 + (size_t)grow * cD + gcol;
        int lidx = grow * 32 + gcol;

        f32x4 acc[4] = {{0.f,0.f,0.f,0.f},{0.f,0.f,0.f,0.f},
                        {0.f,0.f,0.f,0.f},{0.f,0.f,0.f,0.f}};
        uint4 xv = *(const uint4*)(xg);
        uint4 wv = *(const uint4*)(wg);
        for (int s = 0; s < 16; ++s) {
            __syncthreads();
            *(uint4*)&xs[lidx] = xv;
            *(uint4*)&was[lidx] = wv;
            if (s < 15) {
                xv = *(const uint4*)(xg + (s + 1) * 32);
                wv = *(const uint4*)(wg + (s + 1) * 32);
            }
            __syncthreads();
            bf16x8 av = *(const bf16x8*)&xs[(w * 16 + m) * 32 + quad * 8];
#pragma unroll
            for (int g = 0; g < 4; ++g) {
                bf16x8 bv = *(const bf16x8*)&was[(g * 16 + m) * 32 + quad * 8];
                acc[g] = __builtin_amdgcn_mfma_f32_16x16x32_bf16(av, bv, acc[g], 0, 0, 0);
            }
        }
#pragma unroll
        for (int g = 0; g < 4; ++g) {
#pragma unroll
            for (int r4 = 0; r4 < 4; ++r4) {
                int row = w * 16 + quad * 4 + r4;
                h[(size_t)(rowbase + row) * cK + g * 16 + m] = acc[g][r4];
            }
        }
    } else {
        int* part = (int*)shbuf;          // 512 ints
        int rb = blockIdx.x - 256;
        int b = rb >> 6;
        int rowgrp = rb & 63;
        int lane = t & 63, w = t >> 6;
        int rowbase = rowgrp * 64;        // within batch
        const float* t2b = t2 + (size_t)b * cN;
        // 16 composite keys per thread, register-resident (block covers 4096)
        u64 kk[16];
        int jbase = t * 16;
#pragma unroll
        for (int i = 0; i < 16; i += 4) {
            float4 v = *(const float4*)(t2b + jbase + i);
            kk[i+0] = ((u64)f2sort(v.x) << 32) | (u32)(jbase + i + 0);
            kk[i+1] = ((u64)f2sort(v.y) << 32) | (u32)(jbase + i + 1);
            kk[i+2] = ((u64)f2sort(v.z) << 32) | (u32)(jbase + i + 2);
            kk[i+3] = ((u64)f2sort(v.w) << 32) | (u32)(jbase + i + 3);
        }
        // per-lane row thresholds (rows rowbase..rowbase+63 of this batch)
        int myrow = rowbase + lane;
        float t2r = t2b[myrow];
        u64 rowkey = ((u64)f2sort(t2r) << 32) | (u32)myrow;
        u32 rk_lo = (u32)rowkey, rk_hi = (u32)(rowkey >> 32);
        u32 pk_hi = f2sort(-t1[(size_t)b * cN + myrow]);  // pkey low word = 0
        int rankAcc = 0, pAcc = 0;
#pragma unroll 8
        for (int r = 0; r < 64; ++r) {
            u32 tlo = (u32)__builtin_amdgcn_readlane((int)rk_lo, r);
            u32 thi = (u32)__builtin_amdgcn_readlane((int)rk_hi, r);
            u32 tph = (u32)__builtin_amdgcn_readlane((int)pk_hi, r);
            u64 thr = ((u64)thi << 32) | tlo;
            int c1 = 0, c2 = 0;
#pragma unroll
            for (int i = 0; i < 16; ++i) {
                c1 += (int)__popcll(__ballot(kk[i] < thr));
                c2 += (int)__popcll(__ballot((u32)(kk[i] >> 32) < tph));
            }
            if (lane == r) { rankAcc = c1; pAcc = c2; }
        }
        part[w * 64 + lane] = rankAcc;
        part[256 + w * 64 + lane] = pAcc;
        __syncthreads();
        if (t < 64) {
            int row = rowbase + t;
            int rank = part[t] + part[64 + t] + part[128 + t] + part[192 + t];
            int pc   = part[256 + t] + part[320 + t] + part[384 + t] + part[448 + t];
            t2s[(size_t)b * cN + rank] = t2b[row];
            idxs[(size_t)b * cN + rank] = row;
            pidx[(size_t)b * cN + row] = pc;
        }
    }
}

// ---------------------------------------------------------------------------
// k_chunkscan: 128 threads per (batch, chunk-of-16): wave 0 does the E
// (suffix) scan, wave 1 the G (prefix) scan; h rows staged once in LDS.
// 2048 waves total (8/CU) vs the old 1024 single-wave blocks.
// ---------------------------------------------------------------------------
__global__ __launch_bounds__(128) void k_chunkscan(
    const float* __restrict__ t2s, const int* __restrict__ idxs,
    const float* __restrict__ h,
    float* __restrict__ EpL, float* __restrict__ GnL,
    float* __restrict__ eps_l, float* __restrict__ gns_l,
    float* __restrict__ chE, float* __restrict__ chG,
    float* __restrict__ chEs, float* __restrict__ chGs)
{
    __shared__ float hs[cCS][cK];      // 4 KB
    int t = threadIdx.x;
    int lane = t & 63, w = t >> 6;     // w in {0,1}
    int blk = blockIdx.x;
    int c = blk & (cNC - 1);
    int b = blk >> 8;
    int base = b * cN + c * cCS;
    size_t rowbase = ((size_t)b * cNP + c * cCS) * cK;
    int sbase = b * cNP + c * cCS;
    float M2 = t2s[b * cN + cN - 1];
    int   idxv = (lane < 8) ? idxs[base + w * 8 + lane] : 0;
    float t2v  = (lane < cCS) ? t2s[base + lane] : 0.f;

    // each wave gathers 8 h-rows into LDS
#pragma unroll
    for (int ii = 0; ii < 8; ++ii) {
        int i = w * 8 + ii;
        int j = __shfl(idxv, ii, 64);
        hs[i][lane] = h[((size_t)b * cN + j) * cK + lane];
    }
    // per-position exp factors for this wave's scan
    float slope = w ? 0.2f : 1.0f;
    float ev[cCS];
#pragma unroll
    for (int i = 0; i < cCS; ++i)
        ev[i] = __expf(slope * (__shfl(t2v, i, 64) - M2));
    __syncthreads();

    if (c == cNC - 1) {
        if (w == 0) {
            EpL[((size_t)b * cNP + cN) * cK + lane] = 0.f;
            if (lane == 0) eps_l[b * cNP + cN] = 0.f;
        } else {
            GnL[((size_t)b * cNP + cN) * cK + lane] = 0.f;
            if (lane == 0) gns_l[b * cNP + cN] = 0.f;
        }
    }
    float acc = 0.f, accs = 0.f;
    if (w == 0) {
#pragma unroll
        for (int i = cCS - 1; i >= 0; --i) {
            acc += ev[i] * hs[i][lane]; accs += ev[i];
            EpL[rowbase + (size_t)i * cK + lane] = acc;
            if (lane == 0) eps_l[sbase + i] = accs;
        }
        chE[((size_t)b * cNC + c) * cK + lane] = acc;
        if (lane == 0) chEs[b * cNC + c] = accs;
    } else {
#pragma unroll
        for (int i = 0; i < cCS; ++i) {
            GnL[rowbase + (size_t)i * cK + lane] = acc;
            if (lane == 0) gns_l[sbase + i] = accs;
            acc += ev[i] * hs[i][lane]; accs += ev[i];
        }
        chG[((size_t)b * cNC + c) * cK + lane] = acc;
        if (lane == 0) chGs[b * cNC + c] = accs;
    }
}

// ---------------------------------------------------------------------------
// k_offsets: 8 blocks (batch x {E,G}) x 1024 thr (16 waves). Wave w owns 16
// chunks (reg-cached); two-level scan. Scalars: wave 0 shuffle pair-scan.
// ---------------------------------------------------------------------------
__global__ __launch_bounds__(1024) void k_offsets(
    const float* __restrict__ chE, const float* __restrict__ chG,
    const float* __restrict__ chEs, const float* __restrict__ chGs,
    float* __restrict__ ofE, float* __restrict__ ofG,
    float* __restrict__ ofEs, float* __restrict__ ofGs)
{
    __shared__ float wsum[16][64];
    int t = threadIdx.x;
    int lane = t & 63, w = t >> 6;
    int dir = blockIdx.x & 1;          // 0 = E(suffix), 1 = G(prefix)
    int b = blockIdx.x >> 1;
    const float* ch = dir ? chG : chE;
    float* of = dir ? ofG : ofE;
    int c0 = w * 16;

    float cv[16];
    float s = 0.f;
#pragma unroll
    for (int i = 0; i < 16; ++i) {
        cv[i] = ch[((size_t)b * cNC + c0 + i) * cK + lane];
        s += cv[i];
    }
    wsum[w][lane] = s;
    __syncthreads();
    float base = 0.f;
    if (dir == 0) { for (int w2 = w + 1; w2 < 16; ++w2) base += wsum[w2][lane]; }
    else          { for (int w2 = 0; w2 < w; ++w2) base += wsum[w2][lane]; }

    if (dir == 0) {
        float run = base;
#pragma unroll
        for (int i = 15; i >= 0; --i) {
            of[((size_t)b * cNC1 + c0 + i) * cK + lane] = run;
            run += cv[i];
        }
        if (w == 0) of[((size_t)b * cNC1 + cNC) * cK + lane] = 0.f;
    } else {
        float run = base;
#pragma unroll
        for (int i = 0; i < 16; ++i) {
            of[((size_t)b * cNC1 + c0 + i) * cK + lane] = run;
            run += cv[i];
        }
        if (w == 15) of[((size_t)b * cNC1 + cNC) * cK + lane] = run;
    }

    if (w == 0) {
        const float* chs = dir ? chGs : chEs;
        float* ofs = dir ? ofGs : ofEs;
        float e0 = chs[b * cNC + lane * 4 + 0];
        float e1 = chs[b * cNC + lane * 4 + 1];
        float e2 = chs[b * cNC + lane * 4 + 2];
        float e3 = chs[b * cNC + lane * 4 + 3];
        float p = e0 + e1 + e2 + e3;
        if (dir == 0) {
            float s2 = p;
#pragma unroll
            for (int off = 1; off < 64; off <<= 1) {
                float tv = __shfl_down(s2, off, 64);
                if (lane + off < 64) s2 += tv;
            }
            float excl = s2 - p;                  // sum over lanes > lane
            ofs[b * cNC1 + lane * 4 + 0] = excl + e1 + e2 + e3;
            ofs[b * cNC1 + lane * 4 + 1] = excl + e2 + e3;
            ofs[b * cNC1 + lane * 4 + 2] = excl + e3;
            ofs[b * cNC1 + lane * 4 + 3] = excl;
            if (lane == 0) ofs[b * cNC1 + cNC] = 0.f;
        } else {
            float s2 = p;
#pragma unroll
            for (int off = 1; off < 64; off <<= 1) {
                float tv = __shfl_up(s2, off, 64);
                if (lane >= off) s2 += tv;
            }
            float excl = s2 - p;                  // sum over lanes < lane
            ofs[b * cNC1 + lane * 4 + 0] = excl;
            ofs[b * cNC1 + lane * 4 + 1] = excl + e0;
            ofs[b * cNC1 + lane * 4 + 2] = excl + e0 + e1;
            ofs[b * cNC1 + lane * 4 + 3] = excl + e0 + e1 + e2;
            if (lane == 63) ofs[b * cNC1 + cNC] = s2;
        }
    }
}

// ---------------------------------------------------------------------------
// k_out: per row: precomputed split p (from rank pass), combine prefix
// tables, write f32. No binary search.
// ---------------------------------------------------------------------------
__global__ __launch_bounds__(256) void k_out(
    const float* __restrict__ t1, const float* __restrict__ t2s,
    const int* __restrict__ pidx,
    const float* __restrict__ EpL, const float* __restrict__ GnL,
    const float* __restrict__ eps_l, const float* __restrict__ gns_l,
    const float* __restrict__ ofE, const float* __restrict__ ofG,
    const float* __restrict__ ofEs, const float* __restrict__ ofGs,
    const float* __restrict__ bias, float* __restrict__ out)
{
    int tid = threadIdx.x;
    int lane = tid & 63;
    int r = blockIdx.x * 4 + (tid >> 6);
    int b = r >> 12;
    float T1 = t1[r];
    float M2 = t2s[b * cN + cN - 1];
    float smax = T1 + M2;
    float m = fmaxf(smax, 0.2f * smax);      // leaky_relu(smax) = true row max
    float A  = __expf(smax - m);
    float Cc = __expf(0.2f * smax - m);
    int p = pidx[r];
    int c = p >> 4;                          // chunk of p (16-wide)
    size_t pr = ((size_t)b * cNP + p) * cK + lane;
    size_t cr = ((size_t)b * cNC1 + c) * cK + lane;
    float num = A * (EpL[pr] + ofE[cr]) + Cc * (GnL[pr] + ofG[cr]);
    float den = A * (eps_l[(size_t)b * cNP + p] + ofEs[b * cNC1 + c])
              + Cc * (gns_l[(size_t)b * cNP + p] + ofGs[b * cNC1 + c]);
    out[(size_t)r * cK + lane] = num / den + bias[lane];
}

// ---------------------------------------------------------------------------
extern "C" void kernel_launch(void* const* d_in, const int* in_sizes, int n_in,
                              void* d_out, int out_size, void* d_ws, size_t ws_size,
                              hipStream_t stream)
{
    const float* x    = (const float*)d_in[0];
    const float* Wa   = (const float*)d_in[1];
    const float* Wb   = (const float*)d_in[2];
    const float* wbb  = (const float*)d_in[3];
    const float* Wc   = (const float*)d_in[4];
    const float* wcb  = (const float*)d_in[5];
    const float* bias = (const float*)d_in[6];
    float* out = (float*)d_out;

    float* ws = (float*)d_ws;
    float* h     = ws + OFF_H;
    float* t1    = ws + OFF_T1;
    float* t2    = ws + OFF_T2;
    float* t2s   = ws + OFF_T2S;
    int*   idxs  = (int*)(ws + OFF_IDX);
    int*   pidx  = (int*)(ws + OFF_P);
    float* EpL   = ws + OFF_EPL;
    float* GnL   = ws + OFF_GNL;
    float* eps_l = ws + OFF_EPS;
    float* gns_l = ws + OFF_GNS;
    float* chE   = ws + OFF_CHE;
    float* chG   = ws + OFF_CHG;
    float* chEs  = ws + OFF_CHES;
    float* chGs  = ws + OFF_CHGS;
    float* ofE   = ws + OFF_OFE;
    float* ofG   = ws + OFF_OFG;
    float* ofEs  = ws + OFF_OFES;
    float* ofGs  = ws + OFF_OFGS;
    u16*   xb16  = (u16*)(ws + OFF_XB16);
    u16*   wab16 = (u16*)(ws + OFF_WB16);

    k_prep<<<544, 256, 0, stream>>>(x, Wa, Wb, wbb, Wc, wcb, xb16, wab16, t1, t2);
    k_projrank<<<512, 256, 0, stream>>>(xb16, wab16, t1, t2, h, t2s, idxs, pidx);
    k_chunkscan<<<cB * cNC, 128, 0, stream>>>(t2s, idxs, h, EpL, GnL, eps_l, gns_l,
                                              chE, chG, chEs, chGs);
    k_offsets<<<cB * 2, 1024, 0, stream>>>(chE, chG, chEs, chGs, ofE, ofG, ofEs, ofGs);
    k_out<<<cNB / 4, 256, 0, stream>>>(t1, t2s, pidx, EpL, GnL, eps_l, gns_l,
                                       ofE, ofG, ofEs, ofGs, bias, out);
}

// Round 3
// 130.379 us; speedup vs baseline: 1.1046x; 1.1046x over previous
//
#include <hip/hip_runtime.h>
#include <hip/hip_bf16.h>

// Problem constants
constexpr int cB = 4;
constexpr int cN = 4096;
constexpr int cD = 512;
constexpr int cK = 64;
constexpr int cNB = cB * cN;       // 16384 rows
constexpr int cNP = cN + 1;        // 4097 prefix rows
constexpr int cCS = 16;            // chunk size for scans
constexpr int cNC = cN / cCS;      // 256 chunks per batch
constexpr int cNC1 = cNC + 1;      // 257

typedef unsigned short u16;
typedef unsigned int u32;
typedef unsigned long long u64;
typedef __bf16 bf16x8 __attribute__((ext_vector_type(8)));
typedef float f32x4 __attribute__((ext_vector_type(4)));

// ---- workspace layout (in floats) ----
constexpr size_t OFF_H    = 0;                                  // cNB*cK
constexpr size_t OFF_T1   = OFF_H    + (size_t)cNB * cK;        // cNB
constexpr size_t OFF_T2   = OFF_T1   + cNB;                     // cNB
constexpr size_t OFF_T2S  = OFF_T2   + cNB;                     // cNB (sorted)
constexpr size_t OFF_IDX  = OFF_T2S  + cNB;                     // cNB (int)
constexpr size_t OFF_P    = OFF_IDX  + cNB;                     // cNB (int) split point per row
constexpr size_t OFF_EPL  = OFF_P    + cNB;                     // cB*cNP*cK
constexpr size_t OFF_GNL  = OFF_EPL  + (size_t)cB * cNP * cK;   // cB*cNP*cK
constexpr size_t OFF_EPS  = OFF_GNL  + (size_t)cB * cNP * cK;   // cB*cNP
constexpr size_t OFF_GNS  = OFF_EPS  + (size_t)cB * cNP;        // cB*cNP
constexpr size_t OFF_CHE  = OFF_GNS  + (size_t)cB * cNP;        // cB*cNC*cK
constexpr size_t OFF_CHG  = OFF_CHE  + (size_t)cB * cNC * cK;
constexpr size_t OFF_CHES = OFF_CHG  + (size_t)cB * cNC * cK;   // cB*cNC
constexpr size_t OFF_CHGS = OFF_CHES + (size_t)cB * cNC;
constexpr size_t OFF_OFE  = OFF_CHGS + (size_t)cB * cNC;        // cB*cNC1*cK
constexpr size_t OFF_OFG  = OFF_OFE  + (size_t)cB * cNC1 * cK;
constexpr size_t OFF_OFES = OFF_OFG  + (size_t)cB * cNC1 * cK;  // cB*cNC1
constexpr size_t OFF_OFGS = OFF_OFES + (size_t)cB * cNC1;
constexpr size_t OFF_XB16 = OFF_OFGS + (size_t)cB * cNC1;       // cNB*cD u16 = /2 floats
constexpr size_t OFF_WB16 = OFF_XB16 + (size_t)cNB * cD / 2;    // cK*cD u16

__device__ __forceinline__ u16 f2bf(float f) {
    unsigned u = __float_as_uint(f);
    u += 0x7fffu + ((u >> 16) & 1u);   // RNE
    return (u16)(u >> 16);
}
__device__ __forceinline__ u32 pk2(float a, float b) {
    return (u32)f2bf(a) | ((u32)f2bf(b) << 16);
}
// monotone float -> sortable uint (ascending)
__device__ __forceinline__ u32 f2sort(float f) {
    u32 b = __float_as_uint(f);
    u32 mask = (u32)((int)b >> 31);
    return b ^ (mask | 0x80000000u);
}

// ---------------------------------------------------------------------------
// k_prep (544 blocks): blocks <512: one pass over x -> xb16 (bf16) + exact
// f32 t1/t2 via in-block fold of Wa with Wb/Wc. Blocks >=512: Wa -> wab16.
// ---------------------------------------------------------------------------
__global__ __launch_bounds__(256) void k_prep(
    const float* __restrict__ x, const float* __restrict__ Wa,
    const float* __restrict__ Wb, const float* __restrict__ wbb,
    const float* __restrict__ Wc, const float* __restrict__ wcb,
    u16* __restrict__ xb16, u16* __restrict__ wab16,
    float* __restrict__ t1, float* __restrict__ t2)
{
    __shared__ float wabL[cD], wacL[cD];
    int t = threadIdx.x;
    if (blockIdx.x >= 512) {           // wprep slice: 32 blocks x 256 x 4 elems
        int i4 = (((int)blockIdx.x - 512) * 256 + t) * 4;
        float4 v = *(const float4*)(Wa + i4);
        uint2 p = {pk2(v.x, v.y), pk2(v.z, v.w)};
        *(uint2*)(wab16 + i4) = p;
        return;
    }
    float s1a = 0.f, s2a = 0.f, s1b = 0.f, s2b = 0.f;
#pragma unroll 8
    for (int k = 0; k < cK; ++k) {
        float wbk = Wb[k], wck = Wc[k];
        float wa1 = Wa[k * cD + t];
        float wa2 = Wa[k * cD + t + 256];
        s1a += wa1 * wbk; s2a += wa1 * wck;
        s1b += wa2 * wbk; s2b += wa2 * wck;
    }
    wabL[t] = s1a; wacL[t] = s2a; wabL[t + 256] = s1b; wacL[t + 256] = s2b;
    __syncthreads();

    int w = t >> 6, lane = t & 63;
    int d1 = lane * 4, d2 = 256 + lane * 4;
    float4 wbA = *(const float4*)&wabL[d1], wbB = *(const float4*)&wabL[d2];
    float4 wcA = *(const float4*)&wacL[d1], wcB = *(const float4*)&wacL[d2];
    float wbbv = wbb[0], wcbv = wcb[0];
#pragma unroll 2
    for (int rr = 0; rr < 8; ++rr) {
        int row = blockIdx.x * 32 + w * 8 + rr;
        const float* xp = x + (size_t)row * cD;
        float4 a  = *(const float4*)(xp + d1);
        float4 bq = *(const float4*)(xp + d2);
        uint2 pa = {pk2(a.x, a.y), pk2(a.z, a.w)};
        uint2 pb = {pk2(bq.x, bq.y), pk2(bq.z, bq.w)};
        *(uint2*)(xb16 + (size_t)row * cD + d1) = pa;
        *(uint2*)(xb16 + (size_t)row * cD + d2) = pb;
        float p1 = a.x*wbA.x + a.y*wbA.y + a.z*wbA.z + a.w*wbA.w
                 + bq.x*wbB.x + bq.y*wbB.y + bq.z*wbB.z + bq.w*wbB.w;
        float p2 = a.x*wcA.x + a.y*wcA.y + a.z*wcA.z + a.w*wcA.w
                 + bq.x*wcB.x + bq.y*wcB.y + bq.z*wcB.z + bq.w*wcB.w;
#pragma unroll
        for (int off = 32; off > 0; off >>= 1) {
            p1 += __shfl_down(p1, off, 64);
            p2 += __shfl_down(p2, off, 64);
        }
        if (lane == 0) { t1[row] = p1 + wbbv; t2[row] = p2 + wcbv; }
    }
}

// ---------------------------------------------------------------------------
// k_projrank (512 blocks): blocks <256 do the bf16-MFMA GEMM tile (64 rows);
// blocks >=256 do brute-force rank (LDS-staged composite keys). The rank
// loop now ALSO counts p_i = #{t2_j < -t1_i} reusing the same ds_read (hi
// word of the loaded key pair) -- removes k_out's binary search for free.
// LDS union: proj uses 8KB; rank uses 4096 u64 keys (32KB) + 512 int (2KB).
// ---------------------------------------------------------------------------
__global__ __launch_bounds__(256) void k_projrank(
    const u16* __restrict__ xb16, const u16* __restrict__ wab16,
    const float* __restrict__ t1, const float* __restrict__ t2,
    float* __restrict__ h, float* __restrict__ t2s, int* __restrict__ idxs,
    int* __restrict__ pidx)
{
    __shared__ __align__(16) u64 shbuf[4096 + 256];   // 34 KB: keys + part (512 ints)
    int t = threadIdx.x;
    if (blockIdx.x < 256) {
        u16* xs = (u16*)shbuf;
        u16* was = xs + 64 * 32;
        int rowbase = blockIdx.x * 64;
        int w = t >> 6, lane = t & 63, m = lane & 15, quad = lane >> 4;
        int grow = w * 16 + (lane >> 2);
        int gcol = (lane & 3) * 8;
        const u16* xg = xb16 + (size_t)(rowbase + grow) * cD + gcol;
        const u16* wg = wab16 + (size_t)grow * cD + gcol;
        int lidx = grow * 32 + gcol;

        f32x4 acc[4] = {{0.f,0.f,0.f,0.f},{0.f,0.f,0.f,0.f},
                        {0.f,0.f,0.f,0.f},{0.f,0.f,0.f,0.f}};
        uint4 xv = *(const uint4*)(xg);
        uint4 wv = *(const uint4*)(wg);
        for (int s = 0; s < 16; ++s) {
            __syncthreads();
            *(uint4*)&xs[lidx] = xv;
            *(uint4*)&was[lidx] = wv;
            if (s < 15) {
                xv = *(const uint4*)(xg + (s + 1) * 32);
                wv = *(const uint4*)(wg + (s + 1) * 32);
            }
            __syncthreads();
            bf16x8 av = *(const bf16x8*)&xs[(w * 16 + m) * 32 + quad * 8];
#pragma unroll
            for (int g = 0; g < 4; ++g) {
                bf16x8 bv = *(const bf16x8*)&was[(g * 16 + m) * 32 + quad * 8];
                acc[g] = __builtin_amdgcn_mfma_f32_16x16x32_bf16(av, bv, acc[g], 0, 0, 0);
            }
        }
#pragma unroll
        for (int g = 0; g < 4; ++g) {
#pragma unroll
            for (int r4 = 0; r4 < 4; ++r4) {
                int row = w * 16 + quad * 4 + r4;
                h[(size_t)(rowbase + row) * cK + g * 16 + m] = acc[g][r4];
            }
        }
    } else {
        u64* keys = shbuf;
        int* part = (int*)(shbuf + 4096);   // 512 ints
        int rb = blockIdx.x - 256;
        int b = rb >> 6;
        int rowgrp = rb & 63;
        for (int i = t; i < cN; i += 256)
            keys[i] = ((u64)f2sort(t2[b * cN + i]) << 32) | (u32)i;
        __syncthreads();
        int lane = t & 63, subset = t >> 6;
        int myrow = rowgrp * 64 + lane;
        u64 mykey = keys[myrow];
        u32 pk_hi = f2sort(-t1[(size_t)b * cN + myrow]);  // p-threshold hi word
        int s0 = subset * 1024;
        int cnt = 0, cnt2 = 0;
#pragma unroll 8
        for (int kk = 0; kk < 1024; ++kk) {
            u64 kv = keys[s0 + kk];
            cnt  += (kv < mykey) ? 1 : 0;
            cnt2 += ((u32)(kv >> 32) < pk_hi) ? 1 : 0;
        }
        part[subset * 64 + lane] = cnt;
        part[256 + subset * 64 + lane] = cnt2;
        __syncthreads();
        if (t < 64) {
            int jj = rowgrp * 64 + t;
            int rank = part[t] + part[64 + t] + part[128 + t] + part[192 + t];
            int pc   = part[256 + t] + part[320 + t] + part[384 + t] + part[448 + t];
            t2s[b * cN + rank] = t2[b * cN + jj];
            idxs[b * cN + rank] = jj;
            pidx[b * cN + jj] = pc;
        }
    }
}

// ---------------------------------------------------------------------------
// k_chunkscan: one 64-lane wave per (batch, chunk-of-16); E and G scans in
// the same wave (shared gathers, 2x ILP). 1024 blocks.
// ---------------------------------------------------------------------------
__global__ __launch_bounds__(64) void k_chunkscan(
    const float* __restrict__ t2s, const int* __restrict__ idxs,
    const float* __restrict__ h,
    float* __restrict__ EpL, float* __restrict__ GnL,
    float* __restrict__ eps_l, float* __restrict__ gns_l,
    float* __restrict__ chE, float* __restrict__ chG,
    float* __restrict__ chEs, float* __restrict__ chGs)
{
    int lane = threadIdx.x;
    int blk = blockIdx.x;
    int c = blk & (cNC - 1);
    int b = blk >> 8;
    int base = b * cN + c * cCS;
    size_t rowbase = ((size_t)b * cNP + c * cCS) * cK;
    int sbase = b * cNP + c * cCS;
    float M2 = t2s[b * cN + cN - 1];
    int   idxv = (lane < cCS) ? idxs[base + lane] : 0;
    float t2v  = (lane < cCS) ? t2s[base + lane] : 0.f;

    float hv[cCS];
#pragma unroll
    for (int i = 0; i < cCS; ++i) {
        int j = __shfl(idxv, i, 64);
        hv[i] = h[((size_t)b * cN + j) * cK + lane];
    }
    float ee[cCS], gg[cCS];
#pragma unroll
    for (int i = 0; i < cCS; ++i) {
        float d = __shfl(t2v, i, 64) - M2;
        ee[i] = __expf(d);
        gg[i] = __expf(0.2f * d);
    }
    if (c == cNC - 1) {
        EpL[((size_t)b * cNP + cN) * cK + lane] = 0.f;
        GnL[((size_t)b * cNP + cN) * cK + lane] = 0.f;
        if (lane == 0) { eps_l[b * cNP + cN] = 0.f; gns_l[b * cNP + cN] = 0.f; }
    }
    float acc = 0.f, accs = 0.f;
#pragma unroll
    for (int i = cCS - 1; i >= 0; --i) {
        acc += ee[i] * hv[i]; accs += ee[i];
        EpL[rowbase + (size_t)i * cK + lane] = acc;
        if (lane == 0) eps_l[sbase + i] = accs;
    }
    chE[((size_t)b * cNC + c) * cK + lane] = acc;
    if (lane == 0) chEs[b * cNC + c] = accs;
    acc = 0.f; accs = 0.f;
#pragma unroll
    for (int i = 0; i < cCS; ++i) {
        GnL[rowbase + (size_t)i * cK + lane] = acc;
        if (lane == 0) gns_l[sbase + i] = accs;
        acc += gg[i] * hv[i]; accs += gg[i];
    }
    chG[((size_t)b * cNC + c) * cK + lane] = acc;
    if (lane == 0) chGs[b * cNC + c] = accs;
}

// ---------------------------------------------------------------------------
// k_offsets: 8 blocks (batch x {E,G}) x 1024 thr (16 waves). Wave w owns 16
// chunks (reg-cached); two-level scan. Scalars: wave 0 shuffle pair-scan.
// ---------------------------------------------------------------------------
__global__ __launch_bounds__(1024) void k_offsets(
    const float* __restrict__ chE, const float* __restrict__ chG,
    const float* __restrict__ chEs, const float* __restrict__ chGs,
    float* __restrict__ ofE, float* __restrict__ ofG,
    float* __restrict__ ofEs, float* __restrict__ ofGs)
{
    __shared__ float wsum[16][64];
    int t = threadIdx.x;
    int lane = t & 63, w = t >> 6;
    int dir = blockIdx.x & 1;          // 0 = E(suffix), 1 = G(prefix)
    int b = blockIdx.x >> 1;
    const float* ch = dir ? chG : chE;
    float* of = dir ? ofG : ofE;
    int c0 = w * 16;

    float cv[16];
    float s = 0.f;
#pragma unroll
    for (int i = 0; i < 16; ++i) {
        cv[i] = ch[((size_t)b * cNC + c0 + i) * cK + lane];
        s += cv[i];
    }
    wsum[w][lane] = s;
    __syncthreads();
    float base = 0.f;
    if (dir == 0) { for (int w2 = w + 1; w2 < 16; ++w2) base += wsum[w2][lane]; }
    else          { for (int w2 = 0; w2 < w; ++w2) base += wsum[w2][lane]; }

    if (dir == 0) {
        float run = base;
#pragma unroll
        for (int i = 15; i >= 0; --i) {
            of[((size_t)b * cNC1 + c0 + i) * cK + lane] = run;
            run += cv[i];
        }
        if (w == 0) of[((size_t)b * cNC1 + cNC) * cK + lane] = 0.f;
    } else {
        float run = base;
#pragma unroll
        for (int i = 0; i < 16; ++i) {
            of[((size_t)b * cNC1 + c0 + i) * cK + lane] = run;
            run += cv[i];
        }
        if (w == 15) of[((size_t)b * cNC1 + cNC) * cK + lane] = run;
    }

    if (w == 0) {
        const float* chs = dir ? chGs : chEs;
        float* ofs = dir ? ofGs : ofEs;
        float e0 = chs[b * cNC + lane * 4 + 0];
        float e1 = chs[b * cNC + lane * 4 + 1];
        float e2 = chs[b * cNC + lane * 4 + 2];
        float e3 = chs[b * cNC + lane * 4 + 3];
        float p = e0 + e1 + e2 + e3;
        if (dir == 0) {
            float s2 = p;
#pragma unroll
            for (int off = 1; off < 64; off <<= 1) {
                float tv = __shfl_down(s2, off, 64);
                if (lane + off < 64) s2 += tv;
            }
            float excl = s2 - p;                  // sum over lanes > lane
            ofs[b * cNC1 + lane * 4 + 0] = excl + e1 + e2 + e3;
            ofs[b * cNC1 + lane * 4 + 1] = excl + e2 + e3;
            ofs[b * cNC1 + lane * 4 + 2] = excl + e3;
            ofs[b * cNC1 + lane * 4 + 3] = excl;
            if (lane == 0) ofs[b * cNC1 + cNC] = 0.f;
        } else {
            float s2 = p;
#pragma unroll
            for (int off = 1; off < 64; off <<= 1) {
                float tv = __shfl_up(s2, off, 64);
                if (lane >= off) s2 += tv;
            }
            float excl = s2 - p;                  // sum over lanes < lane
            ofs[b * cNC1 + lane * 4 + 0] = excl;
            ofs[b * cNC1 + lane * 4 + 1] = excl + e0;
            ofs[b * cNC1 + lane * 4 + 2] = excl + e0 + e1;
            ofs[b * cNC1 + lane * 4 + 3] = excl + e0 + e1 + e2;
            if (lane == 63) ofs[b * cNC1 + cNC] = s2;
        }
    }
}

// ---------------------------------------------------------------------------
// k_out: per row: precomputed split p (from rank pass), combine prefix
// tables, write f32. No binary search.
// ---------------------------------------------------------------------------
__global__ __launch_bounds__(256) void k_out(
    const float* __restrict__ t1, const float* __restrict__ t2s,
    const int* __restrict__ pidx,
    const float* __restrict__ EpL, const float* __restrict__ GnL,
    const float* __restrict__ eps_l, const float* __restrict__ gns_l,
    const float* __restrict__ ofE, const float* __restrict__ ofG,
    const float* __restrict__ ofEs, const float* __restrict__ ofGs,
    const float* __restrict__ bias, float* __restrict__ out)
{
    int tid = threadIdx.x;
    int lane = tid & 63;
    int r = blockIdx.x * 4 + (tid >> 6);
    int b = r >> 12;
    float T1 = t1[r];
    float M2 = t2s[b * cN + cN - 1];
    float smax = T1 + M2;
    float m = fmaxf(smax, 0.2f * smax);      // leaky_relu(smax) = true row max
    float A  = __expf(smax - m);
    float Cc = __expf(0.2f * smax - m);
    int p = pidx[r];
    int c = p >> 4;                          // chunk of p (16-wide)
    size_t pr = ((size_t)b * cNP + p) * cK + lane;
    size_t cr = ((size_t)b * cNC1 + c) * cK + lane;
    float num = A * (EpL[pr] + ofE[cr]) + Cc * (GnL[pr] + ofG[cr]);
    float den = A * (eps_l[(size_t)b * cNP + p] + ofEs[b * cNC1 + c])
              + Cc * (gns_l[(size_t)b * cNP + p] + ofGs[b * cNC1 + c]);
    out[(size_t)r * cK + lane] = num / den + bias[lane];
}

// ---------------------------------------------------------------------------
extern "C" void kernel_launch(void* const* d_in, const int* in_sizes, int n_in,
                              void* d_out, int out_size, void* d_ws, size_t ws_size,
                              hipStream_t stream)
{
    const float* x    = (const float*)d_in[0];
    const float* Wa   = (const float*)d_in[1];
    const float* Wb   = (const float*)d_in[2];
    const float* wbb  = (const float*)d_in[3];
    const float* Wc   = (const float*)d_in[4];
    const float* wcb  = (const float*)d_in[5];
    const float* bias = (const float*)d_in[6];
    float* out = (float*)d_out;

    float* ws = (float*)d_ws;
    float* h     = ws + OFF_H;
    float* t1    = ws + OFF_T1;
    float* t2    = ws + OFF_T2;
    float* t2s   = ws + OFF_T2S;
    int*   idxs  = (int*)(ws + OFF_IDX);
    int*   pidx  = (int*)(ws + OFF_P);
    float* EpL   = ws + OFF_EPL;
    float* GnL   = ws + OFF_GNL;
    float* eps_l = ws + OFF_EPS;
    float* gns_l = ws + OFF_GNS;
    float* chE   = ws + OFF_CHE;
    float* chG   = ws + OFF_CHG;
    float* chEs  = ws + OFF_CHES;
    float* chGs  = ws + OFF_CHGS;
    float* ofE   = ws + OFF_OFE;
    float* ofG   = ws + OFF_OFG;
    float* ofEs  = ws + OFF_OFES;
    float* ofGs  = ws + OFF_OFGS;
    u16*   xb16  = (u16*)(ws + OFF_XB16);
    u16*   wab16 = (u16*)(ws + OFF_WB16);

    k_prep<<<544, 256, 0, stream>>>(x, Wa, Wb, wbb, Wc, wcb, xb16, wab16, t1, t2);
    k_projrank<<<512, 256, 0, stream>>>(xb16, wab16, t1, t2, h, t2s, idxs, pidx);
    k_chunkscan<<<cB * cNC, 64, 0, stream>>>(t2s, idxs, h, EpL, GnL, eps_l, gns_l,
                                             chE, chG, chEs, chGs);
    k_offsets<<<cB * 2, 1024, 0, stream>>>(chE, chG, chEs, chGs, ofE, ofG, ofEs, ofGs);
    k_out<<<cNB / 4, 256, 0, stream>>>(t1, t2s, pidx, EpL, GnL, eps_l, gns_l,
                                       ofE, ofG, ofEs, ofGs, bias, out);
}